// Round 1
// baseline (12131.508 us; speedup 1.0000x reference)
//
#include <hip/hip_runtime.h>
#include <math.h>

#define NB 1024
#define NHEX 19
#define NVERT 54
#define NEDGE 72
#define NNODE 145   /* hex[0,19) vert[19,73) edge[73,145) */
#define HID 128
#define NH 4
#define NLAYERS 3
#define NREL 5
#define MAXE 144
#define OUTD 256
#define FPLY 14
#define POOLD 398

static __device__ __forceinline__ float bf2f(unsigned short u) {
    unsigned int t = ((unsigned int)u) << 16;
    return __uint_as_float(t);
}
static __device__ __forceinline__ unsigned short f2bf(float f) {
    unsigned int u = __float_as_uint(f);
    unsigned int r = (u + 0x7fffu + ((u >> 16) & 1u)) >> 16;
    return (unsigned short)r;
}

/* ---------------- topology generation (numpy RandomState(0) replica) -------- */
__global__ void k_topo(int* __restrict__ src_all, int* __restrict__ dst_all,
                       int* __restrict__ csr_start, int* __restrict__ csr_eid) {
    if (threadIdx.x != 0 || blockIdx.x != 0) return;
    unsigned int mt[624];
    int mti;
    {   /* mt19937_seed(state, 0) — legacy RandomState scalar seeding */
        unsigned int s = 0u;
        for (int pos = 0; pos < 624; ++pos) {
            mt[pos] = s;
            s = 1812433253u * (s ^ (s >> 30)) + (unsigned int)pos + 1u;
        }
        mti = 624;
    }
    auto next = [&]() -> unsigned int {
        if (mti >= 624) {
            for (int i = 0; i < 624; ++i) {
                unsigned int y = (mt[i] & 0x80000000u) | (mt[(i + 1) % 624] & 0x7fffffffu);
                mt[i] = mt[(i + 397) % 624] ^ (y >> 1) ^ ((y & 1u) ? 0x9908b0dfu : 0u);
            }
            mti = 0;
        }
        unsigned int y = mt[mti++];
        y ^= y >> 11;
        y ^= (y << 7) & 0x9d2c5680u;
        y ^= (y << 15) & 0xefc60000u;
        y ^= y >> 18;
        return y;
    };
    auto ri = [&](unsigned int rng) -> int {  /* uniform 0..rng inclusive, masked rejection */
        unsigned int mask = rng;
        mask |= mask >> 1; mask |= mask >> 2; mask |= mask >> 4;
        mask |= mask >> 8; mask |= mask >> 16;
        unsigned int v;
        do { v = next() & mask; } while (v > rng);
        return (int)v;
    };
    int hv[114], v0[72], v1[72];
    for (int i = 0; i < 114; ++i) hv[i] = ri(53);            /* randint(0,54,(19,6)) */
    for (int i = 0; i < 72; ++i)  v0[i] = ri(53);            /* randint(0,54,72)     */
    for (int i = 0; i < 72; ++i)  v1[i] = (v0[i] + 1 + ri(52)) % 54; /* randint(0,53,72) */

    const int E[5]  = {114, 114, 144, 144, 144};
    const int Nd[5] = {54, 19, 72, 54, 54};
    for (int r = 0; r < 5; ++r) {
        for (int k = 0; k < E[r]; ++k) {
            int s, d;
            if (r == 0)      { s = k / 6;                         d = hv[k]; }
            else if (r == 1) { s = hv[k];                         d = k / 6; }
            else if (r == 2) { s = (k & 1) ? v1[k >> 1] : v0[k >> 1]; d = k >> 1; }
            else if (r == 3) { s = k >> 1;                        d = (k & 1) ? v1[k >> 1] : v0[k >> 1]; }
            else             { s = (k < 72) ? v0[k] : v1[k - 72]; d = (k < 72) ? v1[k] : v0[k - 72]; }
            src_all[r * MAXE + k] = s;
            dst_all[r * MAXE + k] = d;
        }
        int cnt[72];
        for (int d = 0; d < Nd[r]; ++d) cnt[d] = 0;
        for (int k = 0; k < E[r]; ++k) cnt[dst_all[r * MAXE + k]]++;
        int acc = 0;
        for (int d = 0; d < Nd[r]; ++d) { csr_start[r * 73 + d] = acc; acc += cnt[d]; cnt[d] = 0; }
        csr_start[r * 73 + Nd[r]] = acc;
        for (int k = 0; k < E[r]; ++k) {
            int d = dst_all[r * MAXE + k];
            csr_eid[r * MAXE + csr_start[r * 73 + d] + cnt[d]++] = k;
        }
    }
}

/* -------- attention projection vectors: w_as[l,r,h,:] = W[:,h*128:(h+1)*128] @ a_s[h] ---- */
__global__ __launch_bounds__(256) void k_wvec(const float* __restrict__ gat_W,
                                              const float* __restrict__ gat_asrc,
                                              const float* __restrict__ gat_adst,
                                              float* __restrict__ w_as, float* __restrict__ w_ad) {
    int tid = blockIdx.x * 256 + threadIdx.x;
    const int per = NLAYERS * NREL * NH * HID;  /* 7680 */
    if (tid >= 2 * per) return;
    int which = tid / per;
    int rem = tid % per;
    int k = rem % HID;
    int h = (rem / HID) % NH;
    int lr = rem / (HID * NH);
    const float* a = (which ? gat_adst : gat_asrc) + (size_t)(lr * NH + h) * HID;
    const float* W = gat_W + ((size_t)lr * HID + k) * 512 + h * HID;
    float acc = 0.f;
    for (int c = 0; c < HID; ++c) acc += W[c] * a[c];
    (which ? w_ad : w_as)[(size_t)(lr * NH + h) * HID + k] = acc;
}

/* ---------------- input projections ---------------- */
__global__ __launch_bounds__(128) void k_proj(const float* __restrict__ hexf, const float* __restrict__ vertf,
                                              const float* __restrict__ edgef,
                                              const float* __restrict__ Wh, const float* __restrict__ bh,
                                              const float* __restrict__ Wv, const float* __restrict__ bv,
                                              const float* __restrict__ We, const float* __restrict__ be,
                                              float* __restrict__ x) {
    int row = blockIdx.x;          /* b*145 + n */
    int c = threadIdx.x;
    int b = row / NNODE, n = row % NNODE;
    const float *f, *W, *bias;
    int K;
    if (n < NHEX)              { f = hexf  + ((size_t)b * NHEX  + n) * 9;            W = Wh; bias = bh; K = 9; }
    else if (n < NHEX + NVERT) { f = vertf + ((size_t)b * NVERT + (n - NHEX)) * 7;   W = Wv; bias = bv; K = 7; }
    else                       { f = edgef + ((size_t)b * NEDGE + (n - NHEX - NVERT)) * 5; W = We; bias = be; K = 5; }
    float acc = bias[c];
    for (int k = 0; k < K; ++k) acc += f[k] * W[k * HID + c];
    x[(size_t)row * HID + c] = acc;
}

/* ---------------- es/ed: attention logit halves ---------------- */
__global__ __launch_bounds__(256) void k_es(const float* __restrict__ x,
                                            const float* __restrict__ w_as, const float* __restrict__ w_ad,
                                            float* __restrict__ es, float* __restrict__ ed,
                                            int lr, int Ns, int Nd, int srcBase, int dstBase) {
    int tid = blockIdx.x * 256 + threadIdx.x;
    int total = NB * (Ns + Nd) * NH;
    if (tid >= total) return;
    int h = tid & 3;
    int n = (tid >> 2) % (Ns + Nd);
    int b = tid / ((Ns + Nd) * 4);
    bool iss = (n < Ns);
    int node = iss ? (srcBase + n) : (dstBase + (n - Ns));
    const float4* xp = (const float4*)(x + ((size_t)b * NNODE + node) * HID);
    const float4* wp = (const float4*)(((iss ? w_as : w_ad) + (size_t)(lr * NH + h) * HID));
    float acc = 0.f;
#pragma unroll
    for (int k = 0; k < HID / 4; ++k) {
        float4 a = xp[k], w = wp[k];
        acc += a.x * w.x + a.y * w.y + a.z * w.z + a.w * w.w;
    }
    if (iss) es[((size_t)b * 72 + n) * 4 + h] = acc;
    else     ed[((size_t)b * 72 + (n - Ns)) * 4 + h] = acc;
}

/* ---------------- per-dst softmax -> alpha per edge ---------------- */
__global__ __launch_bounds__(256) void k_alpha(const float* __restrict__ es, const float* __restrict__ ed,
                                               const int* __restrict__ src_all, const int* __restrict__ csr_start,
                                               const int* __restrict__ csr_eid,
                                               float* __restrict__ alpha, int r, int Nd) {
    int tid = blockIdx.x * 256 + threadIdx.x;
    int total = NB * Nd * NH;
    if (tid >= total) return;
    int h = tid & 3;
    int d = (tid >> 2) % Nd;
    int b = tid / (Nd * 4);
    int s0 = csr_start[r * 73 + d], s1 = csr_start[r * 73 + d + 1];
    if (s1 == s0) return;
    float edv = ed[((size_t)b * 72 + d) * 4 + h];
    float m = -1e30f;
    for (int i = s0; i < s1; ++i) {
        int e = csr_eid[r * MAXE + i];
        float sc = es[((size_t)b * 72 + src_all[r * MAXE + e]) * 4 + h] + edv;
        sc = (sc >= 0.f) ? sc : 0.2f * sc;
        m = fmaxf(m, sc);
    }
    float ssum = 0.f;
    for (int i = s0; i < s1; ++i) {
        int e = csr_eid[r * MAXE + i];
        float sc = es[((size_t)b * 72 + src_all[r * MAXE + e]) * 4 + h] + edv;
        sc = (sc >= 0.f) ? sc : 0.2f * sc;
        ssum += expf(sc - m);
    }
    float inv = 1.f / (ssum + 1e-16f);
    for (int i = s0; i < s1; ++i) {
        int e = csr_eid[r * MAXE + i];
        float sc = es[((size_t)b * 72 + src_all[r * MAXE + e]) * 4 + h] + edv;
        sc = (sc >= 0.f) ? sc : 0.2f * sc;
        alpha[((size_t)b * MAXE + e) * 4 + h] = expf(sc - m) * inv;
    }
}

/* ------- aggregate + GEMM: agg[dst] += (1/H) * (A_h @ x_src) @ W_h + bias -------- */
template <int NDT>
__global__ __launch_bounds__(256) void k_agg(const float* __restrict__ x, const float* __restrict__ alpha,
                                             const int* __restrict__ src_all, const int* __restrict__ csr_start,
                                             const int* __restrict__ csr_eid,
                                             const float* __restrict__ gat_W, const float* __restrict__ gat_b,
                                             float* __restrict__ agg,
                                             int lr, int r, int srcBase, int dstBase) {
    __shared__ unsigned short yb[NDT * 256];   /* y half (2 heads), bf16 */
    __shared__ float wt[32 * 128];             /* W K-tile */
    int b = blockIdx.x, tid = threadIdx.x;
    constexpr int NOUT = NDT * HID;
    constexpr int NITER = (NOUT + 255) / 256;
    float acc[NITER];
#pragma unroll
    for (int i = 0; i < NITER; ++i) acc[i] = 0.f;
    const float* W = gat_W + (size_t)lr * HID * 512;

    for (int hp = 0; hp < 2; ++hp) {
        __syncthreads();
        /* build y half: cols (h=hp*2+(col>>7), k=col&127) */
        for (int o = tid; o < NDT * 256; o += 256) {
            int d = o >> 8;
            int col = o & 255;
            int h = hp * 2 + (col >> 7);
            int cx = col & 127;
            int s0 = csr_start[r * 73 + d], s1 = csr_start[r * 73 + d + 1];
            float a = 0.f;
            for (int i = s0; i < s1; ++i) {
                int e = csr_eid[r * MAXE + i];
                a += alpha[((size_t)b * MAXE + e) * 4 + h] *
                     x[((size_t)b * NNODE + srcBase + src_all[r * MAXE + e]) * HID + cx];
            }
            yb[o] = f2bf(a);
        }
        for (int kt = 0; kt < 8; ++kt) {
            __syncthreads();
            for (int j = tid; j < 32 * 128; j += 256) {
                int kk = hp * 256 + kt * 32 + (j >> 7);
                wt[j] = W[(size_t)(kk & 127) * 512 + (kk >> 7) * HID + (j & 127)];
            }
            __syncthreads();
#pragma unroll
            for (int i = 0; i < NITER; ++i) {
                int o = tid + (i << 8);
                if (o < NOUT) {
                    int d = o >> 7, c = o & 127;
                    float a = acc[i];
                    const unsigned short* yrow = yb + d * 256 + kt * 32;
                    const float* wc = wt + c;
#pragma unroll
                    for (int kkl = 0; kkl < 32; kkl += 4) {
                        ushort4 yv = *(const ushort4*)(yrow + kkl);
                        a += bf2f(yv.x) * wc[(kkl + 0) * 128];
                        a += bf2f(yv.y) * wc[(kkl + 1) * 128];
                        a += bf2f(yv.z) * wc[(kkl + 2) * 128];
                        a += bf2f(yv.w) * wc[(kkl + 3) * 128];
                    }
                    acc[i] = a;
                }
            }
        }
    }
    const float* bias = gat_b + (size_t)lr * HID;
#pragma unroll
    for (int i = 0; i < NITER; ++i) {
        int o = tid + (i << 8);
        if (o < NOUT) {
            int d = o >> 7, c = o & 127;
            agg[((size_t)b * NNODE + dstBase + d) * HID + c] += 0.25f * acc[i] + bias[c];
        }
    }
}

/* ---------------- residual + LN + relu ---------------- */
__global__ __launch_bounds__(128) void k_ln(const float* __restrict__ agg, float* __restrict__ x,
                                            const float* __restrict__ ln_g, const float* __restrict__ ln_b, int l) {
    __shared__ float red[128];
    int row = blockIdx.x;
    int c = threadIdx.x;
    int n = row % NNODE;
    int t = (n < NHEX) ? 0 : ((n < NHEX + NVERT) ? 1 : 2);
    float v = agg[(size_t)row * HID + c] + x[(size_t)row * HID + c];
    red[c] = v;
    __syncthreads();
    for (int s = 64; s > 0; s >>= 1) { if (c < s) red[c] += red[c + s]; __syncthreads(); }
    float mu = red[0] * (1.f / 128.f);
    __syncthreads();
    float dv = v - mu;
    red[c] = dv * dv;
    __syncthreads();
    for (int s = 64; s > 0; s >>= 1) { if (c < s) red[c] += red[c + s]; __syncthreads(); }
    float var = red[0] * (1.f / 128.f);
    float xn = dv * rsqrtf(var + 1e-5f);
    float out = xn * ln_g[(size_t)(l * 3 + t) * HID + c] + ln_b[(size_t)(l * 3 + t) * HID + c];
    x[(size_t)row * HID + c] = (out > 0.f) ? out : 0.f;
}

/* ---------------- mean pools + player gather ---------------- */
__global__ __launch_bounds__(128) void k_pool(const float* __restrict__ x, const float* __restrict__ playerf,
                                              const int* __restrict__ curp, float* __restrict__ feat) {
    int b = blockIdx.x, c = threadIdx.x;
    const float* xb = x + (size_t)b * NNODE * HID;
    float s0 = 0.f, s1 = 0.f, s2 = 0.f;
    for (int n = 0; n < NHEX; ++n)            s0 += xb[n * HID + c];
    for (int n = NHEX; n < NHEX + NVERT; ++n) s1 += xb[n * HID + c];
    for (int n = NHEX + NVERT; n < NNODE; ++n) s2 += xb[n * HID + c];
    feat[(size_t)b * POOLD + c]       = s0 * (1.f / 19.f);
    feat[(size_t)b * POOLD + 128 + c] = s1 * (1.f / 54.f);
    feat[(size_t)b * POOLD + 256 + c] = s2 * (1.f / 72.f);
    if (c < FPLY) feat[(size_t)b * POOLD + 384 + c] = playerf[((size_t)b * 4 + curp[b]) * FPLY + c];
}

/* ---------------- MLP ---------------- */
__global__ __launch_bounds__(256) void k_mlp1(const float* __restrict__ feat, const float* __restrict__ W1,
                                              const float* __restrict__ b1, float* __restrict__ h1) {
    int tid = blockIdx.x * 256 + threadIdx.x;
    if (tid >= NB * HID) return;
    int j = tid & 127, b = tid >> 7;
    const float* f = feat + (size_t)b * POOLD;
    float acc = b1[j];
    for (int k = 0; k < POOLD; ++k) acc += f[k] * W1[(size_t)k * HID + j];
    h1[tid] = (acc > 0.f) ? acc : 0.f;
}

__global__ __launch_bounds__(256) void k_mlp2(const float* __restrict__ h1, const float* __restrict__ W2,
                                              const float* __restrict__ b2, float* __restrict__ out) {
    int tid = blockIdx.x * 256 + threadIdx.x;
    if (tid >= NB * OUTD) return;
    int o = tid & 255, b = tid >> 8;
    const float* h = h1 + (size_t)b * HID;
    float acc = b2[o];
    for (int j = 0; j < HID; ++j) acc += h[j] * W2[(size_t)j * OUTD + o];
    out[tid] = acc;
}

/* ---------------- workspace layout ---------------- */
static constexpr size_t alignUp(size_t v) { return (v + 255) & ~(size_t)255; }
static constexpr size_t OFF_SRC   = 0;
static constexpr size_t OFF_DSTA  = OFF_SRC + 5 * 144 * 4;
static constexpr size_t OFF_CSRS  = OFF_DSTA + 5 * 144 * 4;
static constexpr size_t OFF_CSRE  = alignUp(OFF_CSRS + 5 * 73 * 4);
static constexpr size_t OFF_WAS   = alignUp(OFF_CSRE + 5 * 144 * 4);
static constexpr size_t OFF_WAD   = OFF_WAS + (size_t)3 * 5 * 4 * 128 * 4;
static constexpr size_t OFF_ES    = OFF_WAD + (size_t)3 * 5 * 4 * 128 * 4;
static constexpr size_t OFF_ED    = OFF_ES + (size_t)NB * 72 * 4 * 4;
static constexpr size_t OFF_ALPHA = OFF_ED + (size_t)NB * 72 * 4 * 4;
static constexpr size_t OFF_FEAT  = OFF_ALPHA + (size_t)NB * 144 * 4 * 4;
static constexpr size_t OFF_H1    = OFF_FEAT + (size_t)NB * POOLD * 4;
static constexpr size_t OFF_X     = alignUp(OFF_H1 + (size_t)NB * HID * 4);
static constexpr size_t OFF_AGG   = OFF_X + (size_t)NB * NNODE * HID * 4;

extern "C" void kernel_launch(void* const* d_in, const int* in_sizes, int n_in,
                              void* d_out, int out_size, void* d_ws, size_t ws_size,
                              hipStream_t stream) {
    (void)in_sizes; (void)n_in; (void)out_size; (void)ws_size;
    const float* hexf   = (const float*)d_in[0];
    const float* vertf  = (const float*)d_in[1];
    const float* edgef  = (const float*)d_in[2];
    const float* playerf= (const float*)d_in[3];
    const float* inhW   = (const float*)d_in[4];
    const float* inhb   = (const float*)d_in[5];
    const float* invW   = (const float*)d_in[6];
    const float* invb   = (const float*)d_in[7];
    const float* ineW   = (const float*)d_in[8];
    const float* ineb   = (const float*)d_in[9];
    const float* gatW   = (const float*)d_in[10];
    const float* gatas  = (const float*)d_in[11];
    const float* gatad  = (const float*)d_in[12];
    const float* gatb   = (const float*)d_in[13];
    const float* lng    = (const float*)d_in[14];
    const float* lnb    = (const float*)d_in[15];
    const float* mW1    = (const float*)d_in[16];
    const float* mb1    = (const float*)d_in[17];
    const float* mW2    = (const float*)d_in[18];
    const float* mb2    = (const float*)d_in[19];
    const int*   curp   = (const int*)d_in[20];
    float* out = (float*)d_out;

    char* ws = (char*)d_ws;
    int* src_all   = (int*)(ws + OFF_SRC);
    int* dst_all   = (int*)(ws + OFF_DSTA);
    int* csr_start = (int*)(ws + OFF_CSRS);
    int* csr_eid   = (int*)(ws + OFF_CSRE);
    float* w_as    = (float*)(ws + OFF_WAS);
    float* w_ad    = (float*)(ws + OFF_WAD);
    float* es      = (float*)(ws + OFF_ES);
    float* ed      = (float*)(ws + OFF_ED);
    float* alpha   = (float*)(ws + OFF_ALPHA);
    float* feat    = (float*)(ws + OFF_FEAT);
    float* h1      = (float*)(ws + OFF_H1);
    float* xbuf    = (float*)(ws + OFF_X);
    float* aggbuf  = (float*)(ws + OFF_AGG);

    static const int hNs[5]      = {19, 54, 54, 72, 54};
    static const int hNd[5]      = {54, 19, 72, 54, 54};
    static const int hSrcBase[5] = {0, 19, 19, 73, 19};
    static const int hDstBase[5] = {19, 0, 73, 19, 19};

    k_topo<<<1, 64, 0, stream>>>(src_all, dst_all, csr_start, csr_eid);
    k_wvec<<<(2 * 3 * 5 * 4 * 128 + 255) / 256, 256, 0, stream>>>(gatW, gatas, gatad, w_as, w_ad);
    k_proj<<<NB * NNODE, 128, 0, stream>>>(hexf, vertf, edgef, inhW, inhb, invW, invb, ineW, ineb, xbuf);

    for (int l = 0; l < NLAYERS; ++l) {
        hipMemsetAsync(aggbuf, 0, (size_t)NB * NNODE * HID * 4, stream);
        for (int r = 0; r < NREL; ++r) {
            int lr = l * 5 + r;
            int Ns = hNs[r], Nd = hNd[r], sb = hSrcBase[r], db = hDstBase[r];
            int tot_es = NB * (Ns + Nd) * 4;
            k_es<<<(tot_es + 255) / 256, 256, 0, stream>>>(xbuf, w_as, w_ad, es, ed, lr, Ns, Nd, sb, db);
            int tot_a = NB * Nd * 4;
            k_alpha<<<(tot_a + 255) / 256, 256, 0, stream>>>(es, ed, src_all, csr_start, csr_eid, alpha, r, Nd);
            if (Nd == 19)
                k_agg<19><<<NB, 256, 0, stream>>>(xbuf, alpha, src_all, csr_start, csr_eid, gatW, gatb, aggbuf, lr, r, sb, db);
            else if (Nd == 54)
                k_agg<54><<<NB, 256, 0, stream>>>(xbuf, alpha, src_all, csr_start, csr_eid, gatW, gatb, aggbuf, lr, r, sb, db);
            else
                k_agg<72><<<NB, 256, 0, stream>>>(xbuf, alpha, src_all, csr_start, csr_eid, gatW, gatb, aggbuf, lr, r, sb, db);
        }
        k_ln<<<NB * NNODE, 128, 0, stream>>>(aggbuf, xbuf, lng, lnb, l);
    }
    k_pool<<<NB, 128, 0, stream>>>(xbuf, playerf, curp, feat);
    k_mlp1<<<(NB * HID + 255) / 256, 256, 0, stream>>>(feat, mW1, mb1, h1);
    k_mlp2<<<(NB * OUTD + 255) / 256, 256, 0, stream>>>(h1, mW2, mb2, out);
}

// Round 2
// 2250.779 us; speedup vs baseline: 5.3899x; 5.3899x over previous
//
#include <hip/hip_runtime.h>
#include <math.h>

#define NB 1024
#define NHEX 19
#define NVERT 54
#define NEDGE 72
#define NNODE 145   /* hex[0,19) vert[19,73) edge[73,145) */
#define HID 128
#define NLAYERS 3
#define MAXE 144
#define OUTD 256
#define FPLY 14
#define POOLD 398

typedef unsigned short ushort_t;
typedef short bf16x8 __attribute__((ext_vector_type(8)));
typedef float f32x4 __attribute__((ext_vector_type(4)));

static __device__ __forceinline__ float bf2f(ushort_t u) {
    unsigned int t = ((unsigned int)u) << 16;
    return __uint_as_float(t);
}
static __device__ __forceinline__ ushort_t f2bf(float f) {
    unsigned int u = __float_as_uint(f);
    unsigned int r = (u + 0x7fffu + ((u >> 16) & 1u)) >> 16;
    return (ushort_t)r;
}

/* ---------------- topology generation (numpy RandomState(0) replica) -------- */
__global__ void k_topo(int* __restrict__ src_all, int* __restrict__ dst_all,
                       int* __restrict__ csr_start, int* __restrict__ csr_src) {
    if (threadIdx.x != 0 || blockIdx.x != 0) return;
    unsigned int mt[624];
    int mti;
    {
        unsigned int s = 0u;
        for (int pos = 0; pos < 624; ++pos) {
            mt[pos] = s;
            s = 1812433253u * (s ^ (s >> 30)) + (unsigned int)pos + 1u;
        }
        mti = 624;
    }
    auto next = [&]() -> unsigned int {
        if (mti >= 624) {
            for (int i = 0; i < 624; ++i) {
                unsigned int y = (mt[i] & 0x80000000u) | (mt[(i + 1) % 624] & 0x7fffffffu);
                mt[i] = mt[(i + 397) % 624] ^ (y >> 1) ^ ((y & 1u) ? 0x9908b0dfu : 0u);
            }
            mti = 0;
        }
        unsigned int y = mt[mti++];
        y ^= y >> 11;
        y ^= (y << 7) & 0x9d2c5680u;
        y ^= (y << 15) & 0xefc60000u;
        y ^= y >> 18;
        return y;
    };
    auto ri = [&](unsigned int rng) -> int {
        unsigned int mask = rng;
        mask |= mask >> 1; mask |= mask >> 2; mask |= mask >> 4;
        mask |= mask >> 8; mask |= mask >> 16;
        unsigned int v;
        do { v = next() & mask; } while (v > rng);
        return (int)v;
    };
    int hv[114], v0[72], v1[72];
    for (int i = 0; i < 114; ++i) hv[i] = ri(53);
    for (int i = 0; i < 72; ++i)  v0[i] = ri(53);
    for (int i = 0; i < 72; ++i)  v1[i] = (v0[i] + 1 + ri(52)) % 54;

    const int E[5]  = {114, 114, 144, 144, 144};
    const int Nd[5] = {54, 19, 72, 54, 54};
    int csr_eid[144];
    for (int r = 0; r < 5; ++r) {
        for (int k = 0; k < E[r]; ++k) {
            int s, d;
            if (r == 0)      { s = k / 6;                         d = hv[k]; }
            else if (r == 1) { s = hv[k];                         d = k / 6; }
            else if (r == 2) { s = (k & 1) ? v1[k >> 1] : v0[k >> 1]; d = k >> 1; }
            else if (r == 3) { s = k >> 1;                        d = (k & 1) ? v1[k >> 1] : v0[k >> 1]; }
            else             { s = (k < 72) ? v0[k] : v1[k - 72]; d = (k < 72) ? v1[k] : v0[k - 72]; }
            src_all[r * MAXE + k] = s;
            dst_all[r * MAXE + k] = d;
        }
        int cnt[72];
        for (int d = 0; d < Nd[r]; ++d) cnt[d] = 0;
        for (int k = 0; k < E[r]; ++k) cnt[dst_all[r * MAXE + k]]++;
        int acc = 0;
        for (int d = 0; d < Nd[r]; ++d) { csr_start[r * 73 + d] = acc; acc += cnt[d]; cnt[d] = 0; }
        csr_start[r * 73 + Nd[r]] = acc;
        for (int k = 0; k < E[r]; ++k) {
            int d = dst_all[r * MAXE + k];
            csr_eid[csr_start[r * 73 + d] + cnt[d]++] = k;
        }
        for (int i = 0; i < E[r]; ++i)
            csr_src[r * MAXE + i] = src_all[r * MAXE + csr_eid[i]];
    }
}

/* -------- attention projection vectors: w_as[l,r,h,:] = W[:,h*128:(h+1)*128] @ a_s[h] ---- */
__global__ __launch_bounds__(256) void k_wvec(const float* __restrict__ gat_W,
                                              const float* __restrict__ gat_asrc,
                                              const float* __restrict__ gat_adst,
                                              float* __restrict__ w_as, float* __restrict__ w_ad) {
    int tid = blockIdx.x * 256 + threadIdx.x;
    const int per = NLAYERS * 5 * 4 * HID;  /* 7680 */
    if (tid >= 2 * per) return;
    int which = tid / per;
    int rem = tid % per;
    int k = rem % HID;
    int h = (rem / HID) % 4;
    int lr = rem / (HID * 4);
    const float* a = (which ? gat_adst : gat_asrc) + (size_t)(lr * 4 + h) * HID;
    const float* W = gat_W + ((size_t)lr * HID + k) * 512 + h * HID;
    float acc = 0.f;
    for (int c = 0; c < HID; ++c) acc += W[c] * a[c];
    (which ? w_ad : w_as)[(size_t)(lr * 4 + h) * HID + k] = acc;
}

/* -------- Wp[lr][h][n][k] = bf16(gat_W[lr][k][h*128+n]) — transposed bf16 weights ------- */
__global__ __launch_bounds__(256) void k_wp(const float* __restrict__ gat_W, ushort_t* __restrict__ Wp) {
    __shared__ ushort_t tr[128 * 130];
    int lrh = blockIdx.x;                 /* 0..59 */
    int lr = lrh >> 2, h = lrh & 3;
    const float* Wsrc = gat_W + (size_t)lr * 128 * 512 + h * 128;
    for (int i = threadIdx.x; i < 128 * 32; i += 256) {
        int k = i >> 5, q = i & 31;
        float4 v = *(const float4*)(Wsrc + (size_t)k * 512 + q * 4);
        int n = q * 4;
        tr[(n + 0) * 130 + k] = f2bf(v.x);
        tr[(n + 1) * 130 + k] = f2bf(v.y);
        tr[(n + 2) * 130 + k] = f2bf(v.z);
        tr[(n + 3) * 130 + k] = f2bf(v.w);
    }
    __syncthreads();
    ushort_t* dst = Wp + (size_t)lrh * 128 * 128;
    for (int i = threadIdx.x; i < 128 * 16; i += 256) {
        int n = i >> 4, q = i & 15;
        const ushort_t* s = tr + n * 130 + q * 8;
        uint4 o;
        o.x = (unsigned)s[0] | ((unsigned)s[1] << 16);
        o.y = (unsigned)s[2] | ((unsigned)s[3] << 16);
        o.z = (unsigned)s[4] | ((unsigned)s[5] << 16);
        o.w = (unsigned)s[6] | ((unsigned)s[7] << 16);
        *(uint4*)(dst + n * 128 + q * 8) = o;
    }
}

/* ---------------- input projections (write f32 + bf16 copies) ---------------- */
__global__ __launch_bounds__(128) void k_proj(const float* __restrict__ hexf, const float* __restrict__ vertf,
                                              const float* __restrict__ edgef,
                                              const float* __restrict__ Wh, const float* __restrict__ bh,
                                              const float* __restrict__ Wv, const float* __restrict__ bv,
                                              const float* __restrict__ We, const float* __restrict__ be,
                                              float* __restrict__ xf, ushort_t* __restrict__ xb) {
    int row = blockIdx.x;          /* b*145 + n */
    int c = threadIdx.x;
    int b = row / NNODE, n = row % NNODE;
    const float *f, *W, *bias;
    int K;
    if (n < NHEX)              { f = hexf  + ((size_t)b * NHEX  + n) * 9;            W = Wh; bias = bh; K = 9; }
    else if (n < NHEX + NVERT) { f = vertf + ((size_t)b * NVERT + (n - NHEX)) * 7;   W = Wv; bias = bv; K = 7; }
    else                       { f = edgef + ((size_t)b * NEDGE + (n - NHEX - NVERT)) * 5; W = We; bias = be; K = 5; }
    float acc = bias[c];
    for (int k = 0; k < K; ++k) acc += f[k] * W[k * HID + c];
    xf[(size_t)row * HID + c] = acc;
    xb[(size_t)row * HID + c] = f2bf(acc);
}

/* =========== fused per-(layer,relation) kernel: logits+softmax+aggregate+MFMA GEMM =========== */
/* MODE: 0 = store agg, 1 = accumulate agg, 2 = LN-finish (no agg read), 3 = agg-read + LN-finish */
template<int NS, int ND, int MODE>
__global__ __launch_bounds__(256, 3) void k_rel(
        float* __restrict__ xf, ushort_t* __restrict__ xb,
        const int* __restrict__ cst_g, const int* __restrict__ csrc_g,
        const float* __restrict__ was, const float* __restrict__ wad,
        const ushort_t* __restrict__ wp, const float* __restrict__ bias,
        float* __restrict__ agg, const float* __restrict__ lg,
        const float* __restrict__ lb, int srcBase, int dstBase, int nE) {
    constexpr int R  = NS + ND;
    constexpr int MT = (ND + 15) / 16;
    /* LDS layout: xs_src [0, NS*256) bf16 | xs_dst [NS*256, R*256) bf16 (dead after logits;
       y overlays it) | esd | alph | cst | csrc.  LN buffer overlays everything at epilogue. */
    constexpr int O_Y   = NS * 256;               /* y_h rows overlay dst slice */
    constexpr int O_ESD = R * 256;
    constexpr int O_AL  = O_ESD + R * 16;
    constexpr int O_CST = O_AL + MAXE * 16;
    constexpr int O_CSR = O_CST + (ND + 1) * 4;
    constexpr int TOT0  = O_CSR + MAXE * 4;
    constexpr int TOT   = (TOT0 > ND * 512 ? TOT0 : ND * 512);
    __shared__ __align__(16) char smem[TOT];
    ushort_t* xs  = (ushort_t*)(smem);
    char*     yb  = smem + O_Y;
    float*    esd = (float*)(smem + O_ESD);
    float*    alph= (float*)(smem + O_AL);
    int*      cst = (int*)(smem + O_CST);
    int*      csrc= (int*)(smem + O_CSR);

    const int b = blockIdx.x, tid = threadIdx.x;
    const int lane = tid & 63, wid = tid >> 6;

    /* ---- stage x rows (src first, then dst), csr ---- */
    for (int i = tid; i < R * 16; i += 256) {
        int row = i >> 4, q = i & 15;
        int node = (row < NS) ? (srcBase + row) : (dstBase + (row - NS));
        uint4 v = *(const uint4*)(xb + ((size_t)b * NNODE + node) * HID + q * 8);
        *(uint4*)(xs + row * 128 + q * 8) = v;
    }
    for (int i = tid; i <= ND; i += 256) cst[i] = cst_g[i];
    for (int i = tid; i < nE; i += 256) csrc[i] = csrc_g[i];
    __syncthreads();

    /* ---- logits es (src rows) / ed (dst rows); rotation avoids bank conflicts ---- */
    for (int i = tid; i < R * 4; i += 256) {
        int row = i >> 2, h = i & 3;
        const float* w = (row < NS ? was : wad) + h * 128;
        const ushort_t* xr = xs + row * 128;
        int rot = (row & 15) * 8;
        float acc = 0.f;
        for (int k = 0; k < 128; ++k) {
            int kk = (k + rot) & 127;
            acc += bf2f(xr[kk]) * w[kk];
        }
        esd[i] = acc;
    }
    __syncthreads();

    /* ---- per-(dst,head) softmax over incident edges -> alph[slot][h] ---- */
    for (int i = tid; i < ND * 4; i += 256) {
        int d = i >> 2, h = i & 3;
        int s0 = cst[d], s1 = cst[d + 1];
        if (s1 == s0) continue;
        float edv = esd[(NS + d) * 4 + h];
        float m = -1e30f;
        for (int j = s0; j < s1; ++j) {
            float sc = esd[csrc[j] * 4 + h] + edv;
            sc = (sc >= 0.f) ? sc : 0.2f * sc;
            m = fmaxf(m, sc);
        }
        float ssum = 0.f;
        for (int j = s0; j < s1; ++j) {
            float sc = esd[csrc[j] * 4 + h] + edv;
            sc = (sc >= 0.f) ? sc : 0.2f * sc;
            float ex = expf(sc - m);
            alph[j * 4 + h] = ex;
            ssum += ex;
        }
        float inv = 1.f / (ssum + 1e-16f);
        for (int j = s0; j < s1; ++j) alph[j * 4 + h] *= inv;
    }
    __syncthreads();

    /* ---- per-head: build y_h (swizzled LDS) then MFMA against Wp ---- */
    f32x4 acc[MT][2];
#pragma unroll
    for (int mt = 0; mt < MT; ++mt) {
        acc[mt][0] = (f32x4){0.f, 0.f, 0.f, 0.f};
        acc[mt][1] = (f32x4){0.f, 0.f, 0.f, 0.f};
    }
    const int nr0 = wid * 32 + (lane & 15);
    const int kc  = (lane >> 4) * 8;

    for (int h = 0; h < 4; ++h) {
        /* issue B-fragment loads early (L2-hot) */
        const ushort_t* wpH = wp + (size_t)h * 128 * 128;
        uint4 bfr[8];
#pragma unroll
        for (int ntl = 0; ntl < 2; ++ntl)
#pragma unroll
            for (int ks = 0; ks < 4; ++ks)
                bfr[ntl * 4 + ks] = *(const uint4*)(wpH + (size_t)(nr0 + ntl * 16) * 128 + ks * 32 + kc);

        /* build y_h[d][c] = sum_e alpha[e][h] * x_src[e][c], bf16, XOR-swizzled */
        for (int i = tid; i < ND * 128; i += 256) {
            int d = i >> 7, c = i & 127;
            int s0 = cst[d], s1 = cst[d + 1];
            float a = 0.f;
            for (int j = s0; j < s1; ++j)
                a += alph[j * 4 + h] * bf2f(xs[csrc[j] * 128 + c]);
            int byte = (d * 256 + c * 2) ^ ((d & 7) << 4);
            *(ushort_t*)(yb + byte) = f2bf(a);
        }
        __syncthreads();

        /* MFMA: acc += y_h @ W_h  (A from LDS swizzled, B from regs) */
#pragma unroll
        for (int ks = 0; ks < 4; ++ks) {
#pragma unroll
            for (int mt = 0; mt < MT; ++mt) {
                int row = mt * 16 + (lane & 15);
                int byte = (row * 256 + ks * 64 + (lane >> 4) * 16) ^ ((row & 7) << 4);
                uint4 av = *(const uint4*)(yb + byte);
                bf16x8 a = __builtin_bit_cast(bf16x8, av);
                acc[mt][0] = __builtin_amdgcn_mfma_f32_16x16x32_bf16(
                    a, __builtin_bit_cast(bf16x8, bfr[ks]), acc[mt][0], 0, 0, 0);
                acc[mt][1] = __builtin_amdgcn_mfma_f32_16x16x32_bf16(
                    a, __builtin_bit_cast(bf16x8, bfr[4 + ks]), acc[mt][1], 0, 0, 0);
            }
        }
        __syncthreads();
    }

    /* ---- epilogue ---- */
    const float bn0 = bias[nr0], bn1 = bias[nr0 + 16];
    if (MODE <= 1) {
#pragma unroll
        for (int mt = 0; mt < MT; ++mt) {
#pragma unroll
            for (int ntl = 0; ntl < 2; ++ntl) {
                int n = nr0 + ntl * 16;
                float bn = ntl ? bn1 : bn0;
#pragma unroll
                for (int reg = 0; reg < 4; ++reg) {
                    int row = mt * 16 + (lane >> 4) * 4 + reg;
                    if (row < ND) {
                        float v = 0.25f * acc[mt][ntl][reg] + bn;
                        size_t gi = ((size_t)b * NVERT + row) * 128 + n;
                        if (MODE == 0) agg[gi] = v;
                        else           agg[gi] += v;
                    }
                }
            }
        }
    } else {
        float* lnb_s = (float*)smem;   /* overlays everything (all dead) */
#pragma unroll
        for (int mt = 0; mt < MT; ++mt) {
#pragma unroll
            for (int ntl = 0; ntl < 2; ++ntl) {
                int n = nr0 + ntl * 16;
                float bn = ntl ? bn1 : bn0;
#pragma unroll
                for (int reg = 0; reg < 4; ++reg) {
                    int row = mt * 16 + (lane >> 4) * 4 + reg;
                    if (row < ND) {
                        float v = 0.25f * acc[mt][ntl][reg] + bn;
                        size_t xgi = ((size_t)b * NNODE + dstBase + row) * 128 + n;
                        if (MODE == 3) v += agg[((size_t)b * NVERT + row) * 128 + n];
                        v += xf[xgi];
                        lnb_s[row * 128 + n] = v;
                    }
                }
            }
        }
        __syncthreads();
        for (int d = wid; d < ND; d += 4) {
            float a0 = lnb_s[d * 128 + lane];
            float a1 = lnb_s[d * 128 + 64 + lane];
            float s = a0 + a1;
            for (int m = 1; m < 64; m <<= 1) s += __shfl_xor(s, m, 64);
            float mu = s * (1.f / 128.f);
            float d0 = a0 - mu, d1 = a1 - mu;
            float q = d0 * d0 + d1 * d1;
            for (int m = 1; m < 64; m <<= 1) q += __shfl_xor(q, m, 64);
            float rs = rsqrtf(q * (1.f / 128.f) + 1e-5f);
            float o0 = fmaxf(d0 * rs * lg[lane] + lb[lane], 0.f);
            float o1 = fmaxf(d1 * rs * lg[64 + lane] + lb[64 + lane], 0.f);
            size_t gi = ((size_t)b * NNODE + dstBase + d) * 128;
            xf[gi + lane] = o0;        xf[gi + 64 + lane] = o1;
            xb[gi + lane] = f2bf(o0);  xb[gi + 64 + lane] = f2bf(o1);
        }
    }
}

/* ---------------- mean pools + player gather ---------------- */
__global__ __launch_bounds__(128) void k_pool(const float* __restrict__ x, const float* __restrict__ playerf,
                                              const int* __restrict__ curp, float* __restrict__ feat) {
    int b = blockIdx.x, c = threadIdx.x;
    const float* xb = x + (size_t)b * NNODE * HID;
    float s0 = 0.f, s1 = 0.f, s2 = 0.f;
    for (int n = 0; n < NHEX; ++n)             s0 += xb[n * HID + c];
    for (int n = NHEX; n < NHEX + NVERT; ++n)  s1 += xb[n * HID + c];
    for (int n = NHEX + NVERT; n < NNODE; ++n) s2 += xb[n * HID + c];
    feat[(size_t)b * POOLD + c]       = s0 * (1.f / 19.f);
    feat[(size_t)b * POOLD + 128 + c] = s1 * (1.f / 54.f);
    feat[(size_t)b * POOLD + 256 + c] = s2 * (1.f / 72.f);
    if (c < FPLY) feat[(size_t)b * POOLD + 384 + c] = playerf[((size_t)b * 4 + curp[b]) * FPLY + c];
}

/* ---------------- MLP ---------------- */
__global__ __launch_bounds__(256) void k_mlp1(const float* __restrict__ feat, const float* __restrict__ W1,
                                              const float* __restrict__ b1, float* __restrict__ h1) {
    int tid = blockIdx.x * 256 + threadIdx.x;
    if (tid >= NB * HID) return;
    int j = tid & 127, b = tid >> 7;
    const float* f = feat + (size_t)b * POOLD;
    float acc = b1[j];
    for (int k = 0; k < POOLD; ++k) acc += f[k] * W1[(size_t)k * HID + j];
    h1[tid] = (acc > 0.f) ? acc : 0.f;
}

__global__ __launch_bounds__(256) void k_mlp2(const float* __restrict__ h1, const float* __restrict__ W2,
                                              const float* __restrict__ b2, float* __restrict__ out) {
    int tid = blockIdx.x * 256 + threadIdx.x;
    if (tid >= NB * OUTD) return;
    int o = tid & 255, b = tid >> 8;
    const float* h = h1 + (size_t)b * HID;
    float acc = b2[o];
    for (int j = 0; j < HID; ++j) acc += h[j] * W2[(size_t)j * OUTD + o];
    out[tid] = acc;
}

/* ---------------- workspace layout ---------------- */
static constexpr size_t alignUp(size_t v) { return (v + 255) & ~(size_t)255; }
static constexpr size_t OFF_CSRS = 0;
static constexpr size_t OFF_CSRC = alignUp(OFF_CSRS + 5 * 73 * 4);
static constexpr size_t OFF_SRC  = alignUp(OFF_CSRC + 5 * MAXE * 4);
static constexpr size_t OFF_DST  = alignUp(OFF_SRC + 5 * MAXE * 4);
static constexpr size_t OFF_WAS  = alignUp(OFF_DST + 5 * MAXE * 4);
static constexpr size_t OFF_WAD  = OFF_WAS + (size_t)15 * 4 * 128 * 4;
static constexpr size_t OFF_WP   = alignUp(OFF_WAD + (size_t)15 * 4 * 128 * 4);
static constexpr size_t OFF_FEAT = alignUp(OFF_WP + (size_t)15 * 4 * 128 * 128 * 2);
static constexpr size_t OFF_H1   = alignUp(OFF_FEAT + (size_t)NB * POOLD * 4);
static constexpr size_t OFF_XF   = alignUp(OFF_H1 + (size_t)NB * HID * 4);
static constexpr size_t OFF_XB   = alignUp(OFF_XF + (size_t)NB * NNODE * HID * 4);
static constexpr size_t OFF_AGG  = alignUp(OFF_XB + (size_t)NB * NNODE * HID * 2);

extern "C" void kernel_launch(void* const* d_in, const int* in_sizes, int n_in,
                              void* d_out, int out_size, void* d_ws, size_t ws_size,
                              hipStream_t stream) {
    (void)in_sizes; (void)n_in; (void)out_size; (void)ws_size;
    const float* hexf   = (const float*)d_in[0];
    const float* vertf  = (const float*)d_in[1];
    const float* edgef  = (const float*)d_in[2];
    const float* playerf= (const float*)d_in[3];
    const float* inhW   = (const float*)d_in[4];
    const float* inhb   = (const float*)d_in[5];
    const float* invW   = (const float*)d_in[6];
    const float* invb   = (const float*)d_in[7];
    const float* ineW   = (const float*)d_in[8];
    const float* ineb   = (const float*)d_in[9];
    const float* gatW   = (const float*)d_in[10];
    const float* gatas  = (const float*)d_in[11];
    const float* gatad  = (const float*)d_in[12];
    const float* gatb   = (const float*)d_in[13];
    const float* lngp   = (const float*)d_in[14];
    const float* lnbp   = (const float*)d_in[15];
    const float* mW1    = (const float*)d_in[16];
    const float* mb1    = (const float*)d_in[17];
    const float* mW2    = (const float*)d_in[18];
    const float* mb2    = (const float*)d_in[19];
    const int*   curp   = (const int*)d_in[20];
    float* out = (float*)d_out;

    char* ws = (char*)d_ws;
    int* csr_start = (int*)(ws + OFF_CSRS);
    int* csr_src   = (int*)(ws + OFF_CSRC);
    int* src_all   = (int*)(ws + OFF_SRC);
    int* dst_all   = (int*)(ws + OFF_DST);
    float* w_as    = (float*)(ws + OFF_WAS);
    float* w_ad    = (float*)(ws + OFF_WAD);
    ushort_t* Wp   = (ushort_t*)(ws + OFF_WP);
    float* feat    = (float*)(ws + OFF_FEAT);
    float* h1      = (float*)(ws + OFF_H1);
    float* xf      = (float*)(ws + OFF_XF);
    ushort_t* xb   = (ushort_t*)(ws + OFF_XB);
    float* aggv    = (float*)(ws + OFF_AGG);

    k_topo<<<1, 64, 0, stream>>>(src_all, dst_all, csr_start, csr_src);
    k_wvec<<<60, 256, 0, stream>>>(gatW, gatas, gatad, w_as, w_ad);
    k_wp<<<60, 256, 0, stream>>>(gatW, Wp);
    k_proj<<<NB * NNODE, 128, 0, stream>>>(hexf, vertf, edgef, inhW, inhb, invW, invb, ineW, ineb, xf, xb);

#define REL_ARGS(rr) xf, xb, csr_start + (rr) * 73, csr_src + (rr) * MAXE, \
        w_as + (size_t)(l * 5 + (rr)) * 512, w_ad + (size_t)(l * 5 + (rr)) * 512, \
        Wp + (size_t)(l * 5 + (rr)) * 4 * 128 * 128, gatb + (size_t)(l * 5 + (rr)) * 128, aggv

    for (int l = 0; l < NLAYERS; ++l) {
        /* r=0: hex->vertex, store agg */
        k_rel<19, 54, 0><<<NB, 256, 0, stream>>>(REL_ARGS(0), nullptr, nullptr, 0, 19, 114);
        /* r=3: edge->vertex, accumulate agg */
        k_rel<72, 54, 1><<<NB, 256, 0, stream>>>(REL_ARGS(3), nullptr, nullptr, 73, 19, 144);
        /* r=1: vertex->hex, LN-finish hex (t=0) */
        k_rel<54, 19, 2><<<NB, 256, 0, stream>>>(REL_ARGS(1),
            lngp + (size_t)(l * 3 + 0) * 128, lnbp + (size_t)(l * 3 + 0) * 128, 19, 0, 114);
        /* r=2: vertex->edge, LN-finish edge (t=2) */
        k_rel<54, 72, 2><<<NB, 256, 0, stream>>>(REL_ARGS(2),
            lngp + (size_t)(l * 3 + 2) * 128, lnbp + (size_t)(l * 3 + 2) * 128, 19, 73, 144);
        /* r=4: vertex->vertex, agg-read + LN-finish vertex (t=1) */
        k_rel<54, 54, 3><<<NB, 256, 0, stream>>>(REL_ARGS(4),
            lngp + (size_t)(l * 3 + 1) * 128, lnbp + (size_t)(l * 3 + 1) * 128, 19, 19, 144);
    }
#undef REL_ARGS

    k_pool<<<NB, 128, 0, stream>>>(xf, playerf, curp, feat);
    k_mlp1<<<(NB * HID + 255) / 256, 256, 0, stream>>>(feat, mW1, mb1, h1);
    k_mlp2<<<(NB * OUTD + 255) / 256, 256, 0, stream>>>(h1, mW2, mb2, out);
}

// Round 3
// 935.945 us; speedup vs baseline: 12.9618x; 2.4048x over previous
//
#include <hip/hip_runtime.h>
#include <math.h>

#define NB 1024
#define NHEX 19
#define NVERT 54
#define NEDGE 72
#define NNODE 145   /* hex[0,19) vert[19,73) edge[73,145) */
#define HID 128
#define NLAYERS 3
#define MAXE 144
#define OUTD 256
#define FPLY 14
#define POOLD 398

typedef unsigned short ushort_t;
typedef short bf16x8 __attribute__((ext_vector_type(8)));
typedef float f32x4 __attribute__((ext_vector_type(4)));

static __device__ __forceinline__ float bf2f(ushort_t u) {
    return __uint_as_float(((unsigned int)u) << 16);
}
static __device__ __forceinline__ ushort_t f2bf(float f) {
    unsigned int u = __float_as_uint(f);
    return (ushort_t)((u + 0x7fffu + ((u >> 16) & 1u)) >> 16);
}
static __device__ __forceinline__ unsigned pk2(float a, float b) {
    return (unsigned)f2bf(a) | ((unsigned)f2bf(b) << 16);
}
static __device__ __forceinline__ float blo(unsigned u) { return __uint_as_float(u << 16); }
static __device__ __forceinline__ float bhi(unsigned u) { return __uint_as_float(u & 0xffff0000u); }

/* ================= topology generation (numpy RandomState(0) replica, parallel) ============ */
__global__ __launch_bounds__(256) void k_topo(int* __restrict__ csr_start_g, int* __restrict__ csr_src_g) {
    __shared__ unsigned mt[624];
    __shared__ int t6[624];
    __shared__ int sc[624];
    __shared__ int hv[114], v0a[72], v1a[72];
    __shared__ int dstl[144], cnt[73], cnt0[73];
    __shared__ int J186;
    const int tid = threadIdx.x;

    if (tid == 0) {   /* serial seeding: chain in registers, writes fire-and-forget */
        unsigned s = 0u;
        for (int i = 0; i < 624; ++i) { mt[i] = s; s = 1812433253u * (s ^ (s >> 30)) + (unsigned)i + 1u; }
    }
    __syncthreads();
    /* twist: 3 parallel sub-phases (read regs -> barrier -> write) */
    {
        unsigned a = 0, bb = 0, c = 0;
        if (tid < 227) { a = mt[tid]; bb = mt[tid + 1]; c = mt[tid + 397]; }
        __syncthreads();
        if (tid < 227) {
            unsigned y = (a & 0x80000000u) | (bb & 0x7fffffffu);
            mt[tid] = c ^ (y >> 1) ^ ((bb & 1u) ? 0x9908b0dfu : 0u);
        }
        __syncthreads();
    }
    {
        int i = 227 + tid;
        unsigned a = 0, bb = 0, c = 0;
        if (tid < 227) { a = mt[i]; bb = mt[i + 1]; c = mt[i - 227]; }
        __syncthreads();
        if (tid < 227) {
            unsigned y = (a & 0x80000000u) | (bb & 0x7fffffffu);
            mt[i] = c ^ (y >> 1) ^ ((bb & 1u) ? 0x9908b0dfu : 0u);
        }
        __syncthreads();
    }
    {
        int i = 454 + tid;
        unsigned a = 0, bb = 0, c = 0;
        if (tid < 170) { a = mt[i]; bb = mt[(i + 1) % 624]; c = mt[i - 227]; }
        __syncthreads();
        if (tid < 170) {
            unsigned y = (a & 0x80000000u) | (bb & 0x7fffffffu);
            mt[i] = c ^ (y >> 1) ^ ((bb & 1u) ? 0x9908b0dfu : 0u);
        }
        __syncthreads();
    }
    /* temper, keep low 6 bits (mask for rng 53/52 is 63) */
    for (int i = tid; i < 624; i += 256) {
        unsigned y = mt[i];
        y ^= y >> 11; y ^= (y << 7) & 0x9d2c5680u; y ^= (y << 15) & 0xefc60000u; y ^= y >> 18;
        t6[i] = (int)(y & 63u);
    }
    __syncthreads();
    /* scan helper: inclusive Hillis-Steele over sc[0..623] */
#define SCAN624()                                                          \
    for (int off = 1; off < 624; off <<= 1) {                              \
        int v0_ = 0, v1_ = 0, v2_ = 0;                                     \
        int i0 = tid, i1 = tid + 256, i2 = tid + 512;                      \
        if (i0 >= off) v0_ = sc[i0 - off];                                 \
        if (i1 >= off) v1_ = sc[i1 - off];                                 \
        if (i2 < 624 && i2 >= off) v2_ = sc[i2 - off];                     \
        __syncthreads();                                                   \
        sc[i0] += v0_; sc[i1] += v1_;                                      \
        if (i2 < 624) sc[i2] += v2_;                                       \
        __syncthreads();                                                   \
    }
    /* pass 1: threshold <=53 for first 186 accepted draws (114 hv + 72 v0) */
    for (int i = tid; i < 624; i += 256) sc[i] = (t6[i] <= 53) ? 1 : 0;
    __syncthreads();
    SCAN624();
    for (int i = tid; i < 624; i += 256) {
        if (t6[i] <= 53) {
            int k = sc[i];
            if (k <= 114) hv[k - 1] = t6[i];
            else if (k <= 186) v0a[k - 115] = t6[i];
            if (k == 186) J186 = i;
        }
    }
    __syncthreads();
    int Jcap = J186;
    /* pass 2: threshold <=52, positions after J186 -> v1 = (v0+1+r)%54 */
    for (int i = tid; i < 624; i += 256) sc[i] = (i > Jcap && t6[i] <= 52) ? 1 : 0;
    __syncthreads();
    SCAN624();
    for (int i = tid; i < 624; i += 256) {
        if (i > Jcap && t6[i] <= 52) {
            int k = sc[i];
            if (k <= 72) v1a[k - 1] = (v0a[k - 1] + 1 + t6[i]) % 54;
        }
    }
    __syncthreads();
#undef SCAN624
    /* build CSR per relation (stable rank scatter) */
    const int En[5] = {114, 114, 144, 144, 144};
    const int Ndn[5] = {54, 19, 72, 54, 54};
    for (int r = 0; r < 5; ++r) {
        int E = En[r], Nd = Ndn[r];
        for (int k = tid; k < E; k += 256) {
            int d;
            if (r == 0)      d = hv[k];
            else if (r == 1) d = k / 6;
            else if (r == 2) d = k >> 1;
            else if (r == 3) d = (k & 1) ? v1a[k >> 1] : v0a[k >> 1];
            else             d = (k < 72) ? v1a[k] : v0a[k - 72];
            dstl[k] = d;
        }
        if (tid < 73) { cnt[tid] = 0; }
        __syncthreads();
        for (int k = tid; k < E; k += 256) atomicAdd(&cnt[dstl[k]], 1);
        __syncthreads();
        if (tid < 73) cnt0[tid] = cnt[tid];
        __syncthreads();
        for (int off = 1; off < 128; off <<= 1) {   /* inclusive scan cnt[0..Nd) */
            int v = 0;
            if (tid < Nd && tid >= off) v = cnt[tid - off];
            __syncthreads();
            if (tid < Nd && tid >= off) cnt[tid] += v;
            __syncthreads();
        }
        if (tid < Nd) csr_start_g[r * 73 + tid] = cnt[tid] - cnt0[tid];
        if (tid == 0) csr_start_g[r * 73 + Nd] = E;
        for (int k = tid; k < E; k += 256) {
            int d = dstl[k];
            int rank = 0;
            for (int j = 0; j < k; ++j) rank += (dstl[j] == d) ? 1 : 0;
            int s;
            if (r == 0)      s = k / 6;
            else if (r == 1) s = hv[k];
            else if (r == 2) s = (k & 1) ? v1a[k >> 1] : v0a[k >> 1];
            else if (r == 3) s = k >> 1;
            else             s = (k < 72) ? v0a[k] : v1a[k - 72];
            csr_src_g[r * 144 + (cnt[d] - cnt0[d]) + rank] = s;
        }
        __syncthreads();
    }
}

/* -------- w_as[l,r,h,:] = W[:,h*128:(h+1)*128] @ a_s[h] — coalesced, block per lr -------- */
__global__ __launch_bounds__(256) void k_wvec(const float* __restrict__ gat_W,
                                              const float* __restrict__ gat_asrc,
                                              const float* __restrict__ gat_adst,
                                              float* __restrict__ w_as, float* __restrict__ w_ad) {
    __shared__ float as_s[512], ad_s[512];
    int lr = blockIdx.x, tid = threadIdx.x;
    for (int i = tid; i < 512; i += 256) {
        as_s[i] = gat_asrc[(size_t)lr * 512 + i];
        ad_s[i] = gat_adst[(size_t)lr * 512 + i];
    }
    __syncthreads();
    const float* W = gat_W + (size_t)lr * 128 * 512;
    int t127 = tid & 127, rhalf = tid >> 7;
    int h = t127 >> 5, c4 = t127 & 31;
    for (int k0 = 0; k0 < 128; k0 += 2) {
        int k = k0 + rhalf;
        float4 wv = *(const float4*)(W + (size_t)k * 512 + h * 128 + c4 * 4);
        const float* a = as_s + h * 128 + c4 * 4;
        const float* d = ad_s + h * 128 + c4 * 4;
        float pa = wv.x * a[0] + wv.y * a[1] + wv.z * a[2] + wv.w * a[3];
        float pd = wv.x * d[0] + wv.y * d[1] + wv.z * d[2] + wv.w * d[3];
        for (int m = 1; m < 32; m <<= 1) { pa += __shfl_xor(pa, m, 64); pd += __shfl_xor(pd, m, 64); }
        if (c4 == 0) {
            w_as[((size_t)lr * 4 + h) * 128 + k] = pa;
            w_ad[((size_t)lr * 4 + h) * 128 + k] = pd;
        }
    }
}

/* -------- Wp[lr][h][n][k] = bf16(gat_W[lr][k][h*128+n]) — transposed bf16 weights ------- */
__global__ __launch_bounds__(256) void k_wp(const float* __restrict__ gat_W, ushort_t* __restrict__ Wp) {
    __shared__ ushort_t tr[128 * 130];
    int lrh = blockIdx.x;
    int lr = lrh >> 2, h = lrh & 3;
    const float* Wsrc = gat_W + (size_t)lr * 128 * 512 + h * 128;
    for (int i = threadIdx.x; i < 128 * 32; i += 256) {
        int k = i >> 5, q = i & 31;
        float4 v = *(const float4*)(Wsrc + (size_t)k * 512 + q * 4);
        int n = q * 4;
        tr[(n + 0) * 130 + k] = f2bf(v.x);
        tr[(n + 1) * 130 + k] = f2bf(v.y);
        tr[(n + 2) * 130 + k] = f2bf(v.z);
        tr[(n + 3) * 130 + k] = f2bf(v.w);
    }
    __syncthreads();
    ushort_t* dst = Wp + (size_t)lrh * 128 * 128;
    for (int i = threadIdx.x; i < 128 * 16; i += 256) {
        int n = i >> 4, q = i & 15;
        const ushort_t* s = tr + n * 130 + q * 8;
        uint4 o;
        o.x = (unsigned)s[0] | ((unsigned)s[1] << 16);
        o.y = (unsigned)s[2] | ((unsigned)s[3] << 16);
        o.z = (unsigned)s[4] | ((unsigned)s[5] << 16);
        o.w = (unsigned)s[6] | ((unsigned)s[7] << 16);
        *(uint4*)(dst + n * 128 + q * 8) = o;
    }
}

/* ---------------- input projections (f32 out), block per batch elem ---------------- */
__global__ __launch_bounds__(256) void k_proj(const float* __restrict__ hexf, const float* __restrict__ vertf,
                                              const float* __restrict__ edgef,
                                              const float* __restrict__ Wh, const float* __restrict__ bh,
                                              const float* __restrict__ Wv, const float* __restrict__ bv,
                                              const float* __restrict__ We, const float* __restrict__ be,
                                              float* __restrict__ xf) {
    __shared__ float Wl[(9 + 7 + 5) * 128];
    __shared__ float bl[3 * 128];
    int b = blockIdx.x, tid = threadIdx.x;
    for (int i = tid; i < 9 * 128; i += 256) Wl[i] = Wh[i];
    for (int i = tid; i < 7 * 128; i += 256) Wl[9 * 128 + i] = Wv[i];
    for (int i = tid; i < 5 * 128; i += 256) Wl[16 * 128 + i] = We[i];
    for (int i = tid; i < 128; i += 256) { }
    if (tid < 128) { bl[tid] = bh[tid]; bl[128 + tid] = bv[tid]; bl[256 + tid] = be[tid]; }
    __syncthreads();
    int c = tid & 127;
    for (int n = tid >> 7; n < NNODE; n += 2) {
        const float* f; const float* W; const float* bias; int K;
        if (n < NHEX)              { f = hexf  + ((size_t)b * NHEX  + n) * 9;                W = Wl;            bias = bl;       K = 9; }
        else if (n < NHEX + NVERT) { f = vertf + ((size_t)b * NVERT + (n - NHEX)) * 7;       W = Wl + 9 * 128;  bias = bl + 128; K = 7; }
        else                       { f = edgef + ((size_t)b * NEDGE + (n - NHEX - NVERT)) * 5; W = Wl + 16 * 128; bias = bl + 256; K = 5; }
        float acc = bias[c];
        for (int k = 0; k < K; ++k) acc += f[k] * W[k * 128 + c];
        xf[((size_t)b * NNODE + n) * HID + c] = acc;
    }
}

/* =========== fused per-(layer, dst-type) kernel =========== */
/* KIND: 0 = to-hex (r1), 1 = to-edge (r2), 2 = to-vertex (r0+r3+r4) ; always LN-finish */
template<int KIND>
__global__ __launch_bounds__(256, (KIND == 0 ? 4 : 2)) void k_fused(
        const float* __restrict__ xf_cur, float* __restrict__ xf_nxt,
        const int* __restrict__ csr_start_g, const int* __restrict__ csr_src_g,
        const float* __restrict__ w_as_g, const float* __restrict__ w_ad_g,
        const ushort_t* __restrict__ Wp_g, const float* __restrict__ gatb_g,
        const float* __restrict__ lg, const float* __restrict__ lb, int l) {
    constexpr int ND      = (KIND == 0 ? 19 : KIND == 1 ? 72 : 54);
    constexpr int NSMAX   = (KIND == 2 ? 72 : 54);
    constexpr int NRELF   = (KIND == 2 ? 3 : 1);
    constexpr int dstBase = (KIND == 0 ? 0 : KIND == 1 ? 73 : 19);
    constexpr int MT      = (ND + 15) / 16;

    constexpr int NS_T[3][3] = {{54, 0, 0}, {54, 0, 0}, {19, 72, 54}};
    constexpr int SB_T[3][3] = {{19, 0, 0}, {19, 0, 0}, {0, 73, 19}};
    constexpr int NE_T[3][3] = {{114, 0, 0}, {144, 0, 0}, {114, 144, 144}};
    constexpr int RI_T[3][3] = {{1, 0, 0}, {2, 0, 0}, {0, 3, 4}};

    constexpr int O_SRC = ND * 256;
    constexpr int O_Y   = O_SRC + NSMAX * 256;
    constexpr int O_ESD = O_Y + ND * 256;
    constexpr int O_AL  = O_ESD + (NSMAX + ND) * 16;
    constexpr int O_CST = O_AL + 144 * 16;
    constexpr int O_CSR = O_CST + 76 * 4;
    constexpr int O_W   = O_CSR + 144 * 4;
    constexpr int TOT   = O_W + 2 * 4 * 132 * 4;
    __shared__ __align__(16) char smem[TOT];
    float* esd  = (float*)(smem + O_ESD);
    float* alph = (float*)(smem + O_AL);
    int*   cst  = (int*)(smem + O_CST);
    int*   csrc = (int*)(smem + O_CSR);
    float* wsm  = (float*)(smem + O_W);

    const int b = blockIdx.x, tid = threadIdx.x;
    const int lane = tid & 63, wid = tid >> 6;
    const float* xcb = xf_cur + (size_t)b * NNODE * HID;

    /* ---- stage dst rows (f32 -> bf16) ---- */
    for (int i = tid; i < ND * 16; i += 256) {
        int row = i >> 4, q = i & 15;
        const float* s = xcb + (size_t)(dstBase + row) * HID + q * 8;
        float4 u0 = *(const float4*)(s), u1 = *(const float4*)(s + 4);
        uint4 o;
        o.x = pk2(u0.x, u0.y); o.y = pk2(u0.z, u0.w);
        o.z = pk2(u1.x, u1.y); o.w = pk2(u1.z, u1.w);
        *(uint4*)(smem + row * 256 + q * 16) = o;
    }

    f32x4 acc[MT][2];
#pragma unroll
    for (int mt = 0; mt < MT; ++mt) {
        acc[mt][0] = (f32x4){0.f, 0.f, 0.f, 0.f};
        acc[mt][1] = (f32x4){0.f, 0.f, 0.f, 0.f};
    }
    const int nr0 = wid * 32 + (lane & 15);
    const int kc  = (lane >> 4) * 8;

#pragma unroll
    for (int ri = 0; ri < NRELF; ++ri) {
        const int NS = NS_T[KIND][ri], srcB = SB_T[KIND][ri], nE = NE_T[KIND][ri], r = RI_T[KIND][ri];
        const int lr = l * 5 + r;
        /* stage src rows, csr, w */
        for (int i = tid; i < NS * 16; i += 256) {
            int row = i >> 4, q = i & 15;
            const float* s = xcb + (size_t)(srcB + row) * HID + q * 8;
            float4 u0 = *(const float4*)(s), u1 = *(const float4*)(s + 4);
            uint4 o;
            o.x = pk2(u0.x, u0.y); o.y = pk2(u0.z, u0.w);
            o.z = pk2(u1.x, u1.y); o.w = pk2(u1.z, u1.w);
            *(uint4*)(smem + O_SRC + row * 256 + q * 16) = o;
        }
        const int* cstg = csr_start_g + r * 73;
        const int* csg  = csr_src_g + r * 144;
        for (int i = tid; i <= ND; i += 256) cst[i] = cstg[i];
        for (int i = tid; i < nE; i += 256) csrc[i] = csg[i];
        const float* wasL = w_as_g + (size_t)lr * 512;
        const float* wadL = w_ad_g + (size_t)lr * 512;
        for (int i = tid; i < 1024; i += 256) {
            int side = i >> 9, h = (i >> 7) & 3, k = i & 127;
            wsm[(side * 4 + h) * 132 + k] = (side ? wadL : wasL)[h * 128 + k];
        }
        __syncthreads();

        /* logits: esd[row*4+h], src rows [0,NS), dst rows [NS,NS+ND) */
        const int R = NS + ND;
        for (int i = tid; i < R * 4; i += 256) {
            int row = i >> 2, h = i & 3;
            bool iss = row < NS;
            const char* xbase = iss ? (smem + O_SRC + row * 256) : (smem + (row - NS) * 256);
            const float* wb = wsm + ((iss ? 0 : 4) + h) * 132;
            float a = 0.f;
#pragma unroll
            for (int kcc = 0; kcc < 8; ++kcc) {
                int c = kcc ^ (row & 7);
                uint4 xv = *(const uint4*)(xbase + c * 16);
                const float* wc = wb + c * 8;
                float4 w0 = *(const float4*)(wc);
                float4 w1 = *(const float4*)(wc + 4);
                a += blo(xv.x) * w0.x + bhi(xv.x) * w0.y + blo(xv.y) * w0.z + bhi(xv.y) * w0.w
                   + blo(xv.z) * w1.x + bhi(xv.z) * w1.y + blo(xv.w) * w1.z + bhi(xv.w) * w1.w;
            }
            esd[i] = a;
        }
        __syncthreads();

        /* per-(dst,head) softmax over incident edges */
        for (int i = tid; i < ND * 4; i += 256) {
            int d = i >> 2, h = i & 3;
            int s0 = cst[d], s1 = cst[d + 1];
            if (s1 == s0) continue;
            float edv = esd[(NS + d) * 4 + h];
            float m = -1e30f;
            for (int j = s0; j < s1; ++j) {
                float scv = esd[csrc[j] * 4 + h] + edv;
                scv = (scv >= 0.f) ? scv : 0.2f * scv;
                m = fmaxf(m, scv);
            }
            float ssum = 0.f;
            for (int j = s0; j < s1; ++j) {
                float scv = esd[csrc[j] * 4 + h] + edv;
                scv = (scv >= 0.f) ? scv : 0.2f * scv;
                float ex = expf(scv - m);
                alph[j * 4 + h] = ex;
                ssum += ex;
            }
            float inv = 1.f / (ssum + 1e-16f);
            for (int j = s0; j < s1; ++j) alph[j * 4 + h] *= inv;
        }
        __syncthreads();

        /* per-head: y build (swizzled) + MFMA */
        for (int h = 0; h < 4; ++h) {
            const ushort_t* wpH = Wp_g + ((size_t)(lr * 4 + h)) * 16384;
            uint4 bfr[8];
#pragma unroll
            for (int ntl = 0; ntl < 2; ++ntl)
#pragma unroll
                for (int ks = 0; ks < 4; ++ks)
                    bfr[ntl * 4 + ks] = *(const uint4*)(wpH + (size_t)(nr0 + ntl * 16) * 128 + ks * 32 + kc);

            for (int i = tid; i < ND * 16; i += 256) {
                int d = i >> 4, c8 = i & 15;
                int s0 = cst[d], s1 = cst[d + 1];
                float a0 = 0.f, a1 = 0.f, a2 = 0.f, a3 = 0.f, a4 = 0.f, a5 = 0.f, a6 = 0.f, a7 = 0.f;
                for (int j = s0; j < s1; ++j) {
                    float al = alph[j * 4 + h];
                    uint4 xv = *(const uint4*)(smem + O_SRC + csrc[j] * 256 + c8 * 16);
                    a0 += al * blo(xv.x); a1 += al * bhi(xv.x);
                    a2 += al * blo(xv.y); a3 += al * bhi(xv.y);
                    a4 += al * blo(xv.z); a5 += al * bhi(xv.z);
                    a6 += al * blo(xv.w); a7 += al * bhi(xv.w);
                }
                uint4 o;
                o.x = pk2(a0, a1); o.y = pk2(a2, a3); o.z = pk2(a4, a5); o.w = pk2(a6, a7);
                *(uint4*)(smem + O_Y + ((d * 256 + c8 * 16) ^ ((d & 7) << 4))) = o;
            }
            __syncthreads();
#pragma unroll
            for (int ks = 0; ks < 4; ++ks) {
#pragma unroll
                for (int mt = 0; mt < MT; ++mt) {
                    int row = mt * 16 + (lane & 15);
                    int byte = (row * 256 + ks * 64 + (lane >> 4) * 16) ^ ((row & 7) << 4);
                    uint4 av = *(const uint4*)(smem + O_Y + byte);
                    bf16x8 a = __builtin_bit_cast(bf16x8, av);
                    acc[mt][0] = __builtin_amdgcn_mfma_f32_16x16x32_bf16(
                        a, __builtin_bit_cast(bf16x8, bfr[ks]), acc[mt][0], 0, 0, 0);
                    acc[mt][1] = __builtin_amdgcn_mfma_f32_16x16x32_bf16(
                        a, __builtin_bit_cast(bf16x8, bfr[4 + ks]), acc[mt][1], 0, 0, 0);
                }
            }
            __syncthreads();
        }
    }

    /* ---- epilogue: bias + residual + LN + relu -> xf_nxt ---- */
    float bn0 = 0.f, bn1 = 0.f;
#pragma unroll
    for (int ri = 0; ri < NRELF; ++ri) {
        const float* bb = gatb_g + (size_t)(l * 5 + RI_T[KIND][ri]) * 128;
        bn0 += bb[nr0]; bn1 += bb[nr0 + 16];
    }
    float* lnb_s = (float*)smem;   /* overlays everything (all dead) */
#pragma unroll
    for (int mt = 0; mt < MT; ++mt) {
#pragma unroll
        for (int ntl = 0; ntl < 2; ++ntl) {
            int n = nr0 + ntl * 16;
            float bn = ntl ? bn1 : bn0;
#pragma unroll
            for (int reg = 0; reg < 4; ++reg) {
                int row = mt * 16 + (lane >> 4) * 4 + reg;
                if (row < ND) {
                    float v = 0.25f * acc[mt][ntl][reg] + bn
                            + xcb[(size_t)(dstBase + row) * HID + n];
                    lnb_s[row * 128 + n] = v;
                }
            }
        }
    }
    __syncthreads();
    for (int d = wid; d < ND; d += 4) {
        float a0 = lnb_s[d * 128 + lane];
        float a1 = lnb_s[d * 128 + 64 + lane];
        float s = a0 + a1;
        for (int m = 1; m < 64; m <<= 1) s += __shfl_xor(s, m, 64);
        float mu = s * (1.f / 128.f);
        float d0 = a0 - mu, d1 = a1 - mu;
        float q = d0 * d0 + d1 * d1;
        for (int m = 1; m < 64; m <<= 1) q += __shfl_xor(q, m, 64);
        float rs = rsqrtf(q * (1.f / 128.f) + 1e-5f);
        float o0 = fmaxf(d0 * rs * lg[lane] + lb[lane], 0.f);
        float o1 = fmaxf(d1 * rs * lg[64 + lane] + lb[64 + lane], 0.f);
        size_t gi = ((size_t)b * NNODE + dstBase + d) * 128;
        xf_nxt[gi + lane] = o0;
        xf_nxt[gi + 64 + lane] = o1;
    }
}

/* ---------------- mean pools + player gather ---------------- */
__global__ __launch_bounds__(128) void k_pool(const float* __restrict__ x, const float* __restrict__ playerf,
                                              const int* __restrict__ curp, float* __restrict__ feat) {
    int b = blockIdx.x, c = threadIdx.x;
    const float* xb = x + (size_t)b * NNODE * HID;
    float s0 = 0.f, s1 = 0.f, s2 = 0.f;
    for (int n = 0; n < NHEX; ++n)             s0 += xb[n * HID + c];
    for (int n = NHEX; n < NHEX + NVERT; ++n)  s1 += xb[n * HID + c];
    for (int n = NHEX + NVERT; n < NNODE; ++n) s2 += xb[n * HID + c];
    feat[(size_t)b * POOLD + c]       = s0 * (1.f / 19.f);
    feat[(size_t)b * POOLD + 128 + c] = s1 * (1.f / 54.f);
    feat[(size_t)b * POOLD + 256 + c] = s2 * (1.f / 72.f);
    if (c < FPLY) feat[(size_t)b * POOLD + 384 + c] = playerf[((size_t)b * 4 + curp[b]) * FPLY + c];
}

/* ---------------- MLP ---------------- */
__global__ __launch_bounds__(256) void k_mlp1(const float* __restrict__ feat, const float* __restrict__ W1,
                                              const float* __restrict__ b1, float* __restrict__ h1) {
    int tid = blockIdx.x * 256 + threadIdx.x;
    if (tid >= NB * HID) return;
    int j = tid & 127, b = tid >> 7;
    const float* f = feat + (size_t)b * POOLD;
    float acc = b1[j];
    for (int k = 0; k < POOLD; ++k) acc += f[k] * W1[(size_t)k * HID + j];
    h1[tid] = (acc > 0.f) ? acc : 0.f;
}

__global__ __launch_bounds__(256) void k_mlp2(const float* __restrict__ h1, const float* __restrict__ W2,
                                              const float* __restrict__ b2, float* __restrict__ out) {
    int tid = blockIdx.x * 256 + threadIdx.x;
    if (tid >= NB * OUTD) return;
    int o = tid & 255, b = tid >> 8;
    const float* h = h1 + (size_t)b * HID;
    float acc = b2[o];
    for (int j = 0; j < HID; ++j) acc += h[j] * W2[(size_t)j * OUTD + o];
    out[tid] = acc;
}

/* ---------------- workspace layout ---------------- */
static constexpr size_t alignUp(size_t v) { return (v + 255) & ~(size_t)255; }
static constexpr size_t OFF_CSRS = 0;
static constexpr size_t OFF_CSRC = alignUp(OFF_CSRS + 5 * 73 * 4);
static constexpr size_t OFF_WAS  = alignUp(OFF_CSRC + 5 * 144 * 4);
static constexpr size_t OFF_WAD  = OFF_WAS + (size_t)15 * 4 * 128 * 4;
static constexpr size_t OFF_WP   = alignUp(OFF_WAD + (size_t)15 * 4 * 128 * 4);
static constexpr size_t OFF_FEAT = alignUp(OFF_WP + (size_t)15 * 4 * 128 * 128 * 2);
static constexpr size_t OFF_H1   = alignUp(OFF_FEAT + (size_t)NB * POOLD * 4);
static constexpr size_t OFF_XA   = alignUp(OFF_H1 + (size_t)NB * HID * 4);
static constexpr size_t OFF_XB2  = OFF_XA + (size_t)NB * NNODE * HID * 4;

extern "C" void kernel_launch(void* const* d_in, const int* in_sizes, int n_in,
                              void* d_out, int out_size, void* d_ws, size_t ws_size,
                              hipStream_t stream) {
    (void)in_sizes; (void)n_in; (void)out_size; (void)ws_size;
    const float* hexf   = (const float*)d_in[0];
    const float* vertf  = (const float*)d_in[1];
    const float* edgef  = (const float*)d_in[2];
    const float* playerf= (const float*)d_in[3];
    const float* inhW   = (const float*)d_in[4];
    const float* inhb   = (const float*)d_in[5];
    const float* invW   = (const float*)d_in[6];
    const float* invb   = (const float*)d_in[7];
    const float* ineW   = (const float*)d_in[8];
    const float* ineb   = (const float*)d_in[9];
    const float* gatW   = (const float*)d_in[10];
    const float* gatas  = (const float*)d_in[11];
    const float* gatad  = (const float*)d_in[12];
    const float* gatb   = (const float*)d_in[13];
    const float* lngp   = (const float*)d_in[14];
    const float* lnbp   = (const float*)d_in[15];
    const float* mW1    = (const float*)d_in[16];
    const float* mb1    = (const float*)d_in[17];
    const float* mW2    = (const float*)d_in[18];
    const float* mb2    = (const float*)d_in[19];
    const int*   curp   = (const int*)d_in[20];
    float* out = (float*)d_out;

    char* ws = (char*)d_ws;
    int* csr_start = (int*)(ws + OFF_CSRS);
    int* csr_src   = (int*)(ws + OFF_CSRC);
    float* w_as    = (float*)(ws + OFF_WAS);
    float* w_ad    = (float*)(ws + OFF_WAD);
    ushort_t* Wp   = (ushort_t*)(ws + OFF_WP);
    float* feat    = (float*)(ws + OFF_FEAT);
    float* h1      = (float*)(ws + OFF_H1);
    float* xfA     = (float*)(ws + OFF_XA);
    float* xfB     = (float*)(ws + OFF_XB2);

    k_topo<<<1, 256, 0, stream>>>(csr_start, csr_src);
    k_wvec<<<15, 256, 0, stream>>>(gatW, gatas, gatad, w_as, w_ad);
    k_wp<<<60, 256, 0, stream>>>(gatW, Wp);
    k_proj<<<NB, 256, 0, stream>>>(hexf, vertf, edgef, inhW, inhb, invW, invb, ineW, ineb, xfA);

    for (int l = 0; l < NLAYERS; ++l) {
        const float* cur = (l & 1) ? xfB : xfA;
        float* nxt = (l & 1) ? xfA : xfB;
        k_fused<0><<<NB, 256, 0, stream>>>(cur, nxt, csr_start, csr_src, w_as, w_ad, Wp, gatb,
                                           lngp + (size_t)(l * 3 + 0) * 128, lnbp + (size_t)(l * 3 + 0) * 128, l);
        k_fused<1><<<NB, 256, 0, stream>>>(cur, nxt, csr_start, csr_src, w_as, w_ad, Wp, gatb,
                                           lngp + (size_t)(l * 3 + 2) * 128, lnbp + (size_t)(l * 3 + 2) * 128, l);
        k_fused<2><<<NB, 256, 0, stream>>>(cur, nxt, csr_start, csr_src, w_as, w_ad, Wp, gatb,
                                           lngp + (size_t)(l * 3 + 1) * 128, lnbp + (size_t)(l * 3 + 1) * 128, l);
    }

    k_pool<<<NB, 128, 0, stream>>>(xfB, playerf, curp, feat);
    k_mlp1<<<(NB * HID + 255) / 256, 256, 0, stream>>>(feat, mW1, mb1, h1);
    k_mlp2<<<(NB * OUTD + 255) / 256, 256, 0, stream>>>(h1, mW2, mb2, out);
}